// Round 11
// baseline (79.053 us; speedup 1.0000x reference)
//
#include <hip/hip_runtime.h>

// YOLO decode, MI355X. R10 = R9b (TS=32, PROW=260, NT wave-contiguous stores,
// 4 blocks/CU -- the 77.9us core) + intra-block 2-stage pipeline:
// tile split into halves (sl 0-15 | 16-31).
//   P0: head + stage half0 -> LDS rows 0-15.           barrier
//   P1: ISSUE half1 global loads -> regs (T14 early);
//       compute/store conf+box+scores half0 (reads rows 0-15);
//       ds_write half1 -> rows 16-31 (T14 late).       barrier
//   P2: compute/store half1.
// Mechanism: R9b's blocks phase-alternate in lockstep (read burst with VALU
// idle, then compute/store burst with read pipe idle -> each stream at ~50%
// duty, VALUBusy 27%, BW ~60% of ceiling). The pipeline mixes the read and
// compute/store streams continuously within each block.

#define NCLS 80
#define NA   3
#define BB   32
#define WW   76
#define HH   76
#define WH   (WW*HH)          // 5776
#define PP   (WH*NA)          // 17328
#define TS   32               // positions per tile
#define HTS  16               // positions per half
#define NTILE ((WH + TS - 1) / TS)   // 181 (last tile: 16 valid -> half1 empty)
#define PROW 260              // LDS row stride (words); 4 mod 32 bank rotate

typedef float f32x4 __attribute__((ext_vector_type(4)));

__global__ __launch_bounds__(256, 4) void yolo_decode_kernel(
    const float* __restrict__ in,       // (B, 255, W, H)
    const float* __restrict__ anchors,  // (2, 3) flat: [d*3 + a]
    float* __restrict__ boxes,          // (B, P, 4)
    float* __restrict__ conf,           // (B, P, 80)
    float* __restrict__ scores)         // (B, P)
{
    __shared__ float  cls[TS * PROW];     // [sl][a*80+c], 33280 B
    __shared__ float  so_buf[TS * NA];
    __shared__ float4 box_buf[TS * NA];

    const int t    = threadIdx.x;
    const int bid  = blockIdx.x;
    const int tile = bid % NTILE;
    const int b    = bid / NTILE;
    const int s0   = tile * TS;
    int valid = WH - s0; if (valid > TS) valid = TS;   // 32 or 16
    int vh0 = valid < HTS ? valid : HTS;               // 16
    int vh1 = valid - HTS; if (vh1 < 0) vh1 = 0; if (vh1 > HTS) vh1 = HTS;

    const float* bplane = in + (size_t)b * 255 * WH;

    // ================= P0 =================
    // head loads (t<96): 32-lane group per anchor, consecutive sl
    int a_h   = t >> 5;
    int sl_h  = t & 31;
    int slc_h = sl_h < valid ? sl_h : valid - 1;
    float tx = 0.f, ty = 0.f, tw = 0.f, th = 0.f, to = 0.f;
    if (t < 96) {
        const float* hp = bplane + (size_t)(a_h * 85) * WH + s0 + slc_h;
        tx = hp[0];
        ty = hp[(size_t)1 * WH];
        tw = hp[(size_t)2 * WH];
        th = hp[(size_t)3 * WH];
        to = hp[(size_t)4 * WH];
    }

    // stage half0: 60 ch-quads x 16 sl = 960 units, <=4/thread
    #pragma unroll
    for (int it = 0; it < 4; ++it) {
        int u = it * 256 + t;
        if (u < 60 * HTS) {
            int qch = u >> 4;              // 0..59
            int sl  = u & 15;              // 0..15 (always < valid)
            int ch0 = qch * 4;
            int a   = ch0 / 80;
            int c0  = ch0 - a * 80;
            const float* gp = bplane + (size_t)(a * 85 + 5 + c0) * WH + s0 + sl;
            *reinterpret_cast<float4*>(&cls[sl * PROW + ch0]) =
                make_float4(gp[0], gp[(size_t)1 * WH],
                            gp[(size_t)2 * WH], gp[(size_t)3 * WH]);
        }
    }

    // head compute -> LDS bufs (t<96)
    if (t < 96) {
        int s = s0 + slc_h;
        int w = s / HH;
        int h = s - w * HH;
        float sx = 1.0f / (1.0f + __expf(-tx));
        float sy = 1.0f / (1.0f + __expf(-ty));
        float bx = (sx + (float)w) * (1.0f / WW);
        float by = (sy + (float)h) * (1.0f / HH);
        float bw = __expf(tw) * anchors[a_h];
        float bh = __expf(th) * anchors[3 + a_h];
        int p = slc_h * 3 + a_h;           // clamped dups write identical data
        box_buf[p] = make_float4(bx - 0.5f * bw, by - 0.5f * bh,
                                 bx + 0.5f * bw, by + 0.5f * bh);
        so_buf[p] = 1.0f / (1.0f + __expf(-to));
    }

    __syncthreads();

    // ================= P1 =================
    // (a) ISSUE half1 global loads into registers (issue-early; u>=960 clamped
    //     to a redundant valid address, never stored)
    float4 pv0, pv1, pv2, pv3;
    {
        #define STAGE_LOAD(IT, PV) { \
            int u = IT * 256 + t; if (u >= 60 * HTS) u = 60 * HTS - 1; \
            int qch = u >> 4; \
            int sl  = (u & 15) + HTS; \
            int slc = sl < valid ? sl : valid - 1; \
            int ch0 = qch * 4; \
            int a   = ch0 / 80; \
            int c0  = ch0 - a * 80; \
            const float* gp = bplane + (size_t)(a * 85 + 5 + c0) * WH + s0 + slc; \
            PV = make_float4(gp[0], gp[(size_t)1 * WH], \
                             gp[(size_t)2 * WH], gp[(size_t)3 * WH]); }
        STAGE_LOAD(0, pv0)
        STAGE_LOAD(1, pv1)
        STAGE_LOAD(2, pv2)
        STAGE_LOAD(3, pv3)
        #undef STAGE_LOAD
    }

    // (b) compute/store conf half0: 960 quads, wave-contiguous 16B NT stores
    #define CONF_HALF(H, VH) { \
        size_t cb = ((size_t)b * PP + (size_t)(s0 + (H) * HTS) * 3) * NCLS; \
        int vq = (VH) * 60; \
        _Pragma("unroll") \
        for (int it = 0; it < 4; ++it) { \
            int q = it * 256 + t; \
            if (q < vq) { \
                int p   = q / 20; \
                int u   = q - p * 20; \
                int sl3 = p / 3; \
                int a   = p - sl3 * 3; \
                int sl  = (H) * HTS + sl3; \
                float4 tv = *reinterpret_cast<const float4*>(&cls[sl * PROW + a * 80 + u * 4]); \
                float so = so_buf[sl * 3 + a]; \
                f32x4 o; \
                o.x = so / (1.0f + __expf(-tv.x)); \
                o.y = so / (1.0f + __expf(-tv.y)); \
                o.z = so / (1.0f + __expf(-tv.z)); \
                o.w = so / (1.0f + __expf(-tv.w)); \
                __builtin_nontemporal_store(o, \
                    reinterpret_cast<f32x4*>(conf + cb + (size_t)q * 4)); \
            } } }

    #define BOXSC_HALF(H, VH) if (t < 48) { \
        int sl3 = t / 3; \
        int a   = t - sl3 * 3; \
        if (sl3 < (VH)) { \
            int sl = (H) * HTS + sl3; \
            int pg = (s0 + sl) * 3 + a; \
            float4 bq = box_buf[sl * 3 + a]; \
            f32x4 bo = {bq.x, bq.y, bq.z, bq.w}; \
            __builtin_nontemporal_store(bo, \
                reinterpret_cast<f32x4*>(boxes + ((size_t)b * PP + pg) * 4)); \
            float mx = -1e30f; \
            _Pragma("unroll") \
            for (int c4 = 0; c4 < 20; ++c4) { \
                float4 v = *reinterpret_cast<const float4*>(&cls[sl * PROW + a * 80 + c4 * 4]); \
                mx = fmaxf(mx, fmaxf(fmaxf(v.x, v.y), fmaxf(v.z, v.w))); } \
            float sc = so_buf[sl * 3 + a] * (1.0f / (1.0f + __expf(-mx))); \
            __builtin_nontemporal_store(sc, scores + (size_t)b * PP + pg); \
        } }

    CONF_HALF(0, vh0)
    BOXSC_HALF(0, vh0)

    // (c) write half1 into LDS rows 16-31 (write-late; disjoint from half0 reads)
    {
        #define STAGE_WRITE(IT, PV) { \
            int u = IT * 256 + t; \
            if (u < 60 * HTS) { \
                int qch = u >> 4; \
                int sl  = (u & 15) + HTS; \
                int ch0 = qch * 4; \
                *reinterpret_cast<float4*>(&cls[sl * PROW + ch0]) = PV; } }
        STAGE_WRITE(0, pv0)
        STAGE_WRITE(1, pv1)
        STAGE_WRITE(2, pv2)
        STAGE_WRITE(3, pv3)
        #undef STAGE_WRITE
    }

    __syncthreads();

    // ================= P2 =================
    CONF_HALF(1, vh1)
    BOXSC_HALF(1, vh1)

    #undef CONF_HALF
    #undef BOXSC_HALF
}

extern "C" void kernel_launch(void* const* d_in, const int* in_sizes, int n_in,
                              void* d_out, int out_size, void* d_ws, size_t ws_size,
                              hipStream_t stream) {
    const float* in      = (const float*)d_in[0];
    const float* anchors = (const float*)d_in[1];

    float* boxes  = (float*)d_out;                       // B*P*4
    float* conf   = boxes + (size_t)BB * PP * 4;         // B*P*80
    float* scores = conf + (size_t)BB * PP * NCLS;       // B*P

    int blocks = BB * NTILE;                             // 5792
    yolo_decode_kernel<<<blocks, 256, 0, stream>>>(in, anchors, boxes, conf, scores);
}